// Round 12
// baseline (201.066 us; speedup 1.0000x reference)
//
#include <hip/hip_runtime.h>
#include <hip/hip_bf16.h>

// EfficientAttention: B=1, H=16, L=4096, D=64, fp32 in/out.
// R11: fuse exp+P-write into the QK loop per-kb so S fragments (sf) never
// hold 32 live regs: total VGPR+AGPR ~152 -> ~112 (<=128), unlocking
// 4 waves/SIMD (2 blocks/CU resident). No new primitives; P layout, LDS ops,
// math all identical to R10 (last green: 137us main).
// Else: 8-wave QBLK=256, dbuf K/V one barrier/tile, setprio, split-K=2,
// XOR-swizzled LDS, (512,2), __expf, f2bf_rz for P/V.

#define LSEQ 4096
#define DH   64
#define NH   16
#define QBLK 256
#define KBLK 64
#define NT   (LSEQ / KBLK)

typedef float  f32x4   __attribute__((ext_vector_type(4)));
typedef short  short8v __attribute__((ext_vector_type(8)));

// float -> bf16 (round-to-nearest-even) — for K and Q staging
__device__ __forceinline__ short f2bf(float f) {
    unsigned int u = __builtin_bit_cast(unsigned int, f);
    u = (u + 0x7FFFu + ((u >> 16) & 1u)) >> 16;
    return (short)u;
}

// float -> bf16 truncation (round toward zero), 1 VALU — for P and V
__device__ __forceinline__ short f2bf_rz(float f) {
    return (short)(__builtin_bit_cast(unsigned int, f) >> 16);
}

__device__ __forceinline__ short8v pack8(const float4& a, const float4& b) {
    short8v f;
    f[0] = f2bf(a.x); f[1] = f2bf(a.y); f[2] = f2bf(a.z); f[3] = f2bf(a.w);
    f[4] = f2bf(b.x); f[5] = f2bf(b.y); f[6] = f2bf(b.z); f[7] = f2bf(b.w);
    return f;
}

// swizzled short-offset of 16B slot `slot` in a 64-short row
#define SWZ(row, slot) ((((slot) ^ ((row) & 7)) << 3))

template <int NSPLIT>
__global__ __launch_bounds__(512, 2)
void attn_fwd(const float* __restrict__ q, const float* __restrict__ k,
              const float* __restrict__ v, float* __restrict__ out,
              float* __restrict__ opart, float* __restrict__ lpart) {
    __shared__ __align__(16) short Klds[2][KBLK][64];   // [buf][key][d], swizzled slots
    __shared__ __align__(16) short Vtlds[2][DH][64];    // [buf][d][key], swizzled slots
    __shared__ __align__(16) short Plds[8][32][64];     // per-wave P [qrow][key], swizzled

    const int t    = threadIdx.x;
    const int w    = t >> 6;        // wave 0..7
    const int lane = t & 63;
    const int g    = lane >> 4;     // 0..3
    const int c    = lane & 15;     // 0..15
    const int h     = blockIdx.y;
    const int qtile = blockIdx.x;
    const int z     = blockIdx.z;
    constexpr int nts = NT / NSPLIT;       // K-tiles handled by this block
    const int kt0   = z * nts;

    const float* qg = q + ((size_t)h * LSEQ + (size_t)qtile * QBLK) * DH;
    const float* kg = k + (size_t)h * LSEQ * DH;
    const float* vg = v + (size_t)h * LSEQ * DH;

    // staging thread mapping (512 threads stage one 64x64 tile each of K, V)
    const int krow  = t >> 3;         // 0..63  (K row)
    const int kslot = t & 7;          // 16B slot within K row
    const int vd    = t & 63;         // V: d index
    const int vs    = t >> 6;         // V: key-slot 0..7 (8 keys each)

    // ---- Q fragments: 2 row-frags (rows w*32+f*16+c), prescaled by 0.125 ----
    short8v qf[2][2];
    #pragma unroll
    for (int f = 0; f < 2; ++f) {
        const int qrow = w * 32 + f * 16 + c;
        #pragma unroll
        for (int h2 = 0; h2 < 2; ++h2) {
            const float* p = &qg[(size_t)qrow * DH + h2 * 32 + g * 8];
            float4 a = *(const float4*)p;
            float4 b = *(const float4*)(p + 4);
            short8v fr;
            fr[0] = f2bf(a.x * 0.125f); fr[1] = f2bf(a.y * 0.125f);
            fr[2] = f2bf(a.z * 0.125f); fr[3] = f2bf(a.w * 0.125f);
            fr[4] = f2bf(b.x * 0.125f); fr[5] = f2bf(b.y * 0.125f);
            fr[6] = f2bf(b.z * 0.125f); fr[7] = f2bf(b.w * 0.125f);
            qf[f][h2] = fr;
        }
    }

    f32x4 o[2][4];
    #pragma unroll
    for (int f = 0; f < 2; ++f)
        #pragma unroll
        for (int i = 0; i < 4; ++i) o[f][i] = (f32x4){0.f, 0.f, 0.f, 0.f};
    float lp[2][4] = {{0.f,0.f,0.f,0.f},{0.f,0.f,0.f,0.f}};

    float4 kreg[2];   // one 32B K slice per thread
    float  vreg[8];   // 8 V scalars per thread

    // ---- prologue: load+stage tile 0, then issue loads for tile 1 ----
    {
        const int keyP = kt0 * KBLK;
        const float* p = &kg[(size_t)(keyP + krow) * DH + kslot * 8];
        kreg[0] = *(const float4*)p;
        kreg[1] = *(const float4*)(p + 4);
        #pragma unroll
        for (int j = 0; j < 8; ++j)
            vreg[j] = vg[(size_t)(keyP + vs * 8 + j) * DH + vd];
        *(short8v*)&Klds[0][krow][SWZ(krow, kslot)] = pack8(kreg[0], kreg[1]);
        short8v f8;
        #pragma unroll
        for (int j = 0; j < 8; ++j) f8[j] = f2bf_rz(vreg[j]);
        *(short8v*)&Vtlds[0][vd][SWZ(vd, vs)] = f8;
    }
    if (nts > 1) {
        const int key1 = (kt0 + 1) * KBLK;
        const float* p = &kg[(size_t)(key1 + krow) * DH + kslot * 8];
        kreg[0] = *(const float4*)p;
        kreg[1] = *(const float4*)(p + 4);
        #pragma unroll
        for (int j = 0; j < 8; ++j)
            vreg[j] = vg[(size_t)(key1 + vs * 8 + j) * DH + vd];
    }
    __syncthreads();

    short* Pw = &Plds[w][0][0];

    for (int it = 0; it < nts; ++it) {
        const int cur = it & 1;
        const int nxt = cur ^ 1;

        // ---- write-early: stage tile it+1 (regs loaded one iter ago) ----
        if (it + 1 < nts) {
            *(short8v*)&Klds[nxt][krow][SWZ(krow, kslot)] = pack8(kreg[0], kreg[1]);
            short8v f8;
            #pragma unroll
            for (int j = 0; j < 8; ++j) f8[j] = f2bf_rz(vreg[j]);
            *(short8v*)&Vtlds[nxt][vd][SWZ(vd, vs)] = f8;
        }
        // ---- issue loads for tile it+2 ----
        if (it + 2 < nts) {
            const int key2 = (kt0 + it + 2) * KBLK;
            const float* p = &kg[(size_t)(key2 + krow) * DH + kslot * 8];
            kreg[0] = *(const float4*)p;
            kreg[1] = *(const float4*)(p + 4);
            #pragma unroll
            for (int j = 0; j < 8; ++j)
                vreg[j] = vg[(size_t)(key2 + vs * 8 + j) * DH + vd];
        }

        // ---- fused: per 16-key block, QK^T then exp + P-write immediately ----
        #pragma unroll
        for (int kb = 0; kb < 4; ++kb) {
            const int kr = kb * 16 + c;
            const int sw = c & 7;
            short8v k0 = *(const short8v*)&Klds[cur][kr][(g       ^ sw) << 3];
            short8v k1 = *(const short8v*)&Klds[cur][kr][((4 + g) ^ sw) << 3];
            __builtin_amdgcn_s_setprio(1);
            f32x4 sf0 = (f32x4){0.f, 0.f, 0.f, 0.f};
            f32x4 sf1 = (f32x4){0.f, 0.f, 0.f, 0.f};
            sf0 = __builtin_amdgcn_mfma_f32_16x16x32_bf16(qf[0][0], k0, sf0, 0, 0, 0);
            sf0 = __builtin_amdgcn_mfma_f32_16x16x32_bf16(qf[0][1], k1, sf0, 0, 0, 0);
            sf1 = __builtin_amdgcn_mfma_f32_16x16x32_bf16(qf[1][0], k0, sf1, 0, 0, 0);
            sf1 = __builtin_amdgcn_mfma_f32_16x16x32_bf16(qf[1][1], k1, sf1, 0, 0, 0);
            __builtin_amdgcn_s_setprio(0);
            const int col = kb * 16 + c;
            const int so  = col >> 3;
            const int si  = col & 7;
            #pragma unroll
            for (int f = 0; f < 2; ++f) {
                const f32x4& s = f ? sf1 : sf0;
                #pragma unroll
                for (int r = 0; r < 4; ++r) {
                    float pv = __expf(s[r]);
                    lp[f][r] += pv;
                    const int row = f * 16 + 4 * g + r;
                    Pw[row * 64 + SWZ(row, so) + si] = f2bf_rz(pv);
                }
            }
        }

        // ---- O += P V ----
        #pragma unroll
        for (int kt2 = 0; kt2 < 2; ++kt2) {
            const int slot = kt2 * 4 + g;
            short8v pa0 = *(const short8v*)&Pw[(c)      * 64 + SWZ(c, slot)];
            short8v pa1 = *(const short8v*)&Pw[(16 + c) * 64 + SWZ(16 + c, slot)];
            __builtin_amdgcn_s_setprio(1);
            #pragma unroll
            for (int nf = 0; nf < 4; ++nf) {
                const int vrow = nf * 16 + c;
                short8v vb = *(const short8v*)&Vtlds[cur][vrow][SWZ(vrow, slot)];
                o[0][nf] = __builtin_amdgcn_mfma_f32_16x16x32_bf16(pa0, vb, o[0][nf], 0, 0, 0);
                o[1][nf] = __builtin_amdgcn_mfma_f32_16x16x32_bf16(pa1, vb, o[1][nf], 0, 0, 0);
            }
            __builtin_amdgcn_s_setprio(0);
        }

        __syncthreads();   // buf[nxt] writes visible; everyone done with buf[cur]
    }

    // ---- epilogue: reduce l over 16-lane groups ----
    #pragma unroll
    for (int mask = 1; mask < 16; mask <<= 1) {
        #pragma unroll
        for (int f = 0; f < 2; ++f)
            #pragma unroll
            for (int r = 0; r < 4; ++r)
                lp[f][r] += __shfl_xor(lp[f][r], mask, 64);
    }

    if (NSPLIT == 1) {
        float* og = out + ((size_t)h * LSEQ + (size_t)qtile * QBLK) * DH;
        #pragma unroll
        for (int f = 0; f < 2; ++f)
            #pragma unroll
            for (int r = 0; r < 4; ++r) {
                float inv = 1.0f / lp[f][r];
                const int qrow = w * 32 + f * 16 + 4 * g + r;
                #pragma unroll
                for (int nf = 0; nf < 4; ++nf)
                    og[(size_t)qrow * DH + nf * 16 + c] = o[f][nf][r] * inv;
            }
    } else {
        float* op = opart + ((size_t)(z * NH + h) * LSEQ + (size_t)qtile * QBLK) * DH;
        float* lprow = lpart + (size_t)(z * NH + h) * LSEQ + (size_t)qtile * QBLK;
        #pragma unroll
        for (int f = 0; f < 2; ++f)
            #pragma unroll
            for (int r = 0; r < 4; ++r) {
                const int qrow = w * 32 + f * 16 + 4 * g + r;
                #pragma unroll
                for (int nf = 0; nf < 4; ++nf)
                    op[(size_t)qrow * DH + nf * 16 + c] = o[f][nf][r];
                if (c == 0) lprow[qrow] = lp[f][r];
            }
    }
}

// merge 2 splits: out = (O0+O1) / (l0+l1)
__global__ __launch_bounds__(256)
void reduce_split(const float* __restrict__ opart, const float* __restrict__ lpart,
                  float* __restrict__ out) {
    const size_t OSZ  = (size_t)NH * LSEQ * DH;     // floats per split
    const size_t LSZ  = (size_t)NH * LSEQ;
    const size_t TOT4 = OSZ / 4;
    for (size_t i4 = (size_t)blockIdx.x * blockDim.x + threadIdx.x; i4 < TOT4;
         i4 += (size_t)gridDim.x * blockDim.x) {
        const size_t i   = i4 * 4;
        const size_t row = i >> 6;                  // / DH
        float4 a = *(const float4*)&opart[i];
        float4 b = *(const float4*)&opart[OSZ + i];
        float inv = 1.0f / (lpart[row] + lpart[LSZ + row]);
        float4 r;
        r.x = (a.x + b.x) * inv; r.y = (a.y + b.y) * inv;
        r.z = (a.z + b.z) * inv; r.w = (a.w + b.w) * inv;
        *(float4*)&out[i] = r;
    }
}

extern "C" void kernel_launch(void* const* d_in, const int* in_sizes, int n_in,
                              void* d_out, int out_size, void* d_ws, size_t ws_size,
                              hipStream_t stream) {
    const float* q = (const float*)d_in[0];
    const float* k = (const float*)d_in[1];
    const float* v = (const float*)d_in[2];
    float* out = (float*)d_out;

    const size_t OSZ = (size_t)NH * LSEQ * DH;      // floats per split
    const size_t LSZ = (size_t)NH * LSEQ;
    const size_t need = (2 * OSZ + 2 * LSZ) * sizeof(float);

    if (ws_size >= need) {
        float* opart = (float*)d_ws;
        float* lpart = opart + 2 * OSZ;
        attn_fwd<2><<<dim3(LSEQ / QBLK, NH, 2), dim3(512), 0, stream>>>(q, k, v, out, opart, lpart);
        reduce_split<<<dim3(2048), dim3(256), 0, stream>>>(opart, lpart, out);
    } else {
        attn_fwd<1><<<dim3(LSEQ / QBLK, NH, 1), dim3(512), 0, stream>>>(q, k, v, out, nullptr, nullptr);
    }
}

// Round 13
// 192.013 us; speedup vs baseline: 1.0471x; 1.0471x over previous
//
#include <hip/hip_runtime.h>
#include <hip/hip_bf16.h>

// EfficientAttention: B=1, H=16, L=4096, D=64, fp32 in/out.
// R12: in-register P (R8 structure) with PROVEN primitives only.
// Swapped QK^T: ssw = mfma(K, Q) -> lane(c,g) holds S[keys kb*16+4g+r][qrow=c].
// exp via __expf (proven), bf16 pair-packing via shift/mask truncation
// (proven f2bf_rz), PV A-fragment rebuilt with ds_bpermute (ISA-doc semantics;
// mapping re-derived from facts pinned by 12 rounds of passing kernels).
// Plds DELETED: LDS 64KB->32KB; per-wave-tile LDS ops 20 b128 + 32 b16 ->
// 16 b128 + 16 bpermute. R8's failure triangulated to cvtpk/exp2 primitives
// (quarantined), not this mapping.
// Else identical to R11: 8-wave QBLK=256, dbuf K/V one barrier/tile, setprio,
// split-K=2, XOR-swizzled LDS, (512,2).

#define LSEQ 4096
#define DH   64
#define NH   16
#define QBLK 256
#define KBLK 64
#define NT   (LSEQ / KBLK)

typedef float  f32x4   __attribute__((ext_vector_type(4)));
typedef short  short8v __attribute__((ext_vector_type(8)));
typedef int    int4v   __attribute__((ext_vector_type(4)));

// float -> bf16 (round-to-nearest-even) — for K and Q staging
__device__ __forceinline__ short f2bf(float f) {
    unsigned int u = __builtin_bit_cast(unsigned int, f);
    u = (u + 0x7FFFu + ((u >> 16) & 1u)) >> 16;
    return (short)u;
}

// float -> bf16 truncation (round toward zero), 1 VALU — for V staging
__device__ __forceinline__ short f2bf_rz(float f) {
    return (short)(__builtin_bit_cast(unsigned int, f) >> 16);
}

// pack two positive floats as truncated bf16 pair: lo -> [15:0], hi -> [31:16]
__device__ __forceinline__ int pack_rz(float lo, float hi) {
    return (int)((__builtin_bit_cast(unsigned int, lo) >> 16) |
                 (__builtin_bit_cast(unsigned int, hi) & 0xffff0000u));
}

__device__ __forceinline__ short8v pack8(const float4& a, const float4& b) {
    short8v f;
    f[0] = f2bf(a.x); f[1] = f2bf(a.y); f[2] = f2bf(a.z); f[3] = f2bf(a.w);
    f[4] = f2bf(b.x); f[5] = f2bf(b.y); f[6] = f2bf(b.z); f[7] = f2bf(b.w);
    return f;
}

// swizzled short-offset of 16B slot `slot` in a 64-short row
#define SWZ(row, slot) ((((slot) ^ ((row) & 7)) << 3))

template <int NSPLIT>
__global__ __launch_bounds__(512, 2)
void attn_fwd(const float* __restrict__ q, const float* __restrict__ k,
              const float* __restrict__ v, float* __restrict__ out,
              float* __restrict__ opart, float* __restrict__ lpart) {
    __shared__ __align__(16) short Klds[2][KBLK][64];   // [buf][key][d], swizzled slots
    __shared__ __align__(16) short Vtlds[2][DH][64];    // [buf][d][key], swizzled slots

    const int t    = threadIdx.x;
    const int w    = t >> 6;        // wave 0..7
    const int lane = t & 63;
    const int g    = lane >> 4;     // 0..3
    const int c    = lane & 15;     // 0..15
    const bool ghi = lane >= 32;    // selects H=1 (keys 16..31 of the half)
    const int h     = blockIdx.y;
    const int qtile = blockIdx.x;
    const int z     = blockIdx.z;
    constexpr int nts = NT / NSPLIT;       // K-tiles handled by this block
    const int kt0   = z * nts;

    // bpermute source byte-addrs: lane c + 16*gs, gs = 2*(g&1) (+1 for addrB)
    const int addrA = (c + ((lane & 16) << 1)) << 2;
    const int addrB = addrA + 64;

    const float* qg = q + ((size_t)h * LSEQ + (size_t)qtile * QBLK) * DH;
    const float* kg = k + (size_t)h * LSEQ * DH;
    const float* vg = v + (size_t)h * LSEQ * DH;

    // staging thread mapping (512 threads stage one 64x64 tile each of K, V)
    const int krow  = t >> 3;         // 0..63  (K row)
    const int kslot = t & 7;          // 16B slot within K row
    const int vd    = t & 63;         // V: d index
    const int vs    = t >> 6;         // V: key-slot 0..7 (8 keys each)

    // ---- Q fragments: rows w*32+f*16+c, prescaled by 0.125 (fed as B-op) ----
    short8v qf[2][2];
    #pragma unroll
    for (int f = 0; f < 2; ++f) {
        const int qrow = w * 32 + f * 16 + c;
        #pragma unroll
        for (int h2 = 0; h2 < 2; ++h2) {
            const float* p = &qg[(size_t)qrow * DH + h2 * 32 + g * 8];
            float4 a = *(const float4*)p;
            float4 b = *(const float4*)(p + 4);
            short8v fr;
            fr[0] = f2bf(a.x * 0.125f); fr[1] = f2bf(a.y * 0.125f);
            fr[2] = f2bf(a.z * 0.125f); fr[3] = f2bf(a.w * 0.125f);
            fr[4] = f2bf(b.x * 0.125f); fr[5] = f2bf(b.y * 0.125f);
            fr[6] = f2bf(b.z * 0.125f); fr[7] = f2bf(b.w * 0.125f);
            qf[f][h2] = fr;
        }
    }

    f32x4 o[2][4];
    #pragma unroll
    for (int f = 0; f < 2; ++f)
        #pragma unroll
        for (int i = 0; i < 4; ++i) o[f][i] = (f32x4){0.f, 0.f, 0.f, 0.f};
    float lp[2] = {0.f, 0.f};   // per-lane denom partials for q-row c

    float4 kreg[2];   // one 32B K slice per thread
    float  vreg[8];   // 8 V scalars per thread

    // ---- prologue: load+stage tile 0, then issue loads for tile 1 ----
    {
        const int keyP = kt0 * KBLK;
        const float* p = &kg[(size_t)(keyP + krow) * DH + kslot * 8];
        kreg[0] = *(const float4*)p;
        kreg[1] = *(const float4*)(p + 4);
        #pragma unroll
        for (int j = 0; j < 8; ++j)
            vreg[j] = vg[(size_t)(keyP + vs * 8 + j) * DH + vd];
        *(short8v*)&Klds[0][krow][SWZ(krow, kslot)] = pack8(kreg[0], kreg[1]);
        short8v f8;
        #pragma unroll
        for (int j = 0; j < 8; ++j) f8[j] = f2bf_rz(vreg[j]);
        *(short8v*)&Vtlds[0][vd][SWZ(vd, vs)] = f8;
    }
    if (nts > 1) {
        const int key1 = (kt0 + 1) * KBLK;
        const float* p = &kg[(size_t)(key1 + krow) * DH + kslot * 8];
        kreg[0] = *(const float4*)p;
        kreg[1] = *(const float4*)(p + 4);
        #pragma unroll
        for (int j = 0; j < 8; ++j)
            vreg[j] = vg[(size_t)(key1 + vs * 8 + j) * DH + vd];
    }
    __syncthreads();

    for (int it = 0; it < nts; ++it) {
        const int cur = it & 1;
        const int nxt = cur ^ 1;

        // ---- write-early: stage tile it+1 (regs loaded one iter ago) ----
        if (it + 1 < nts) {
            *(short8v*)&Klds[nxt][krow][SWZ(krow, kslot)] = pack8(kreg[0], kreg[1]);
            short8v f8;
            #pragma unroll
            for (int j = 0; j < 8; ++j) f8[j] = f2bf_rz(vreg[j]);
            *(short8v*)&Vtlds[nxt][vd][SWZ(vd, vs)] = f8;
        }
        // ---- issue loads for tile it+2 ----
        if (it + 2 < nts) {
            const int key2 = (kt0 + it + 2) * KBLK;
            const float* p = &kg[(size_t)(key2 + krow) * DH + kslot * 8];
            kreg[0] = *(const float4*)p;
            kreg[1] = *(const float4*)(p + 4);
            #pragma unroll
            for (int j = 0; j < 8; ++j)
                vreg[j] = vg[(size_t)(key2 + vs * 8 + j) * DH + vd];
        }

        // ---- per 32-key half: swapped QK^T -> in-reg exp/pack -> exchange -> PV ----
        #pragma unroll
        for (int kb2 = 0; kb2 < 2; ++kb2) {
            int pk[2][2][2];    // [f][H][pair]: packed bf16 P, qrow=c, keys 4g+r
            #pragma unroll
            for (int H = 0; H < 2; ++H) {
                const int kb = 2 * kb2 + H;
                const int kr = kb * 16 + c;
                const int sw = c & 7;
                short8v k0 = *(const short8v*)&Klds[cur][kr][(g       ^ sw) << 3];
                short8v k1 = *(const short8v*)&Klds[cur][kr][((4 + g) ^ sw) << 3];
                __builtin_amdgcn_s_setprio(1);
                f32x4 s0 = (f32x4){0.f, 0.f, 0.f, 0.f};
                f32x4 s1 = (f32x4){0.f, 0.f, 0.f, 0.f};
                s0 = __builtin_amdgcn_mfma_f32_16x16x32_bf16(k0, qf[0][0], s0, 0, 0, 0);
                s0 = __builtin_amdgcn_mfma_f32_16x16x32_bf16(k1, qf[0][1], s0, 0, 0, 0);
                s1 = __builtin_amdgcn_mfma_f32_16x16x32_bf16(k0, qf[1][0], s1, 0, 0, 0);
                s1 = __builtin_amdgcn_mfma_f32_16x16x32_bf16(k1, qf[1][1], s1, 0, 0, 0);
                __builtin_amdgcn_s_setprio(0);
                #pragma unroll
                for (int f = 0; f < 2; ++f) {
                    const f32x4& s = f ? s1 : s0;
                    float p0 = __expf(s[0]);
                    float p1 = __expf(s[1]);
                    float p2 = __expf(s[2]);
                    float p3 = __expf(s[3]);
                    lp[f] += (p0 + p1) + (p2 + p3);
                    pk[f][H][0] = pack_rz(p0, p1);
                    pk[f][H][1] = pack_rz(p2, p3);
                }
            }

            // ---- exchange: build PV A-fragment P[qrow=c][keys kb2*32+8g..8g+7] ----
            short8v af[2];
            #pragma unroll
            for (int f = 0; f < 2; ++f) {
                int lo0 = __builtin_amdgcn_ds_bpermute(addrA, pk[f][0][0]);
                int hi0 = __builtin_amdgcn_ds_bpermute(addrA, pk[f][1][0]);
                int lo1 = __builtin_amdgcn_ds_bpermute(addrA, pk[f][0][1]);
                int hi1 = __builtin_amdgcn_ds_bpermute(addrA, pk[f][1][1]);
                int lo2 = __builtin_amdgcn_ds_bpermute(addrB, pk[f][0][0]);
                int hi2 = __builtin_amdgcn_ds_bpermute(addrB, pk[f][1][0]);
                int lo3 = __builtin_amdgcn_ds_bpermute(addrB, pk[f][0][1]);
                int hi3 = __builtin_amdgcn_ds_bpermute(addrB, pk[f][1][1]);
                int4v a4;
                a4[0] = ghi ? hi0 : lo0;
                a4[1] = ghi ? hi1 : lo1;
                a4[2] = ghi ? hi2 : lo2;
                a4[3] = ghi ? hi3 : lo3;
                af[f] = __builtin_bit_cast(short8v, a4);
            }

            // ---- O += P V for this 32-key half ----
            const int slot = kb2 * 4 + g;
            __builtin_amdgcn_s_setprio(1);
            #pragma unroll
            for (int nf = 0; nf < 4; ++nf) {
                const int vrow = nf * 16 + c;
                short8v vb = *(const short8v*)&Vtlds[cur][vrow][SWZ(vrow, slot)];
                o[0][nf] = __builtin_amdgcn_mfma_f32_16x16x32_bf16(af[0], vb, o[0][nf], 0, 0, 0);
                o[1][nf] = __builtin_amdgcn_mfma_f32_16x16x32_bf16(af[1], vb, o[1][nf], 0, 0, 0);
            }
            __builtin_amdgcn_s_setprio(0);
        }

        __syncthreads();   // buf[nxt] writes visible; everyone done with buf[cur]
    }

    // ---- epilogue: lane(c,*) accumulates full denom for q-row c ----
    #pragma unroll
    for (int f = 0; f < 2; ++f) {
        lp[f] += __shfl_xor(lp[f], 16, 64);
        lp[f] += __shfl_xor(lp[f], 32, 64);
    }

    if (NSPLIT == 1) {
        float* og = out + ((size_t)h * LSEQ + (size_t)qtile * QBLK) * DH;
        #pragma unroll
        for (int f = 0; f < 2; ++f) {
            #pragma unroll
            for (int r = 0; r < 4; ++r) {
                // denom for q-row 4g+r lives at lane (c=4g+r, g=0)
                int db = __builtin_amdgcn_ds_bpermute((4 * g + r) << 2,
                                                      __builtin_bit_cast(int, lp[f]));
                float inv = 1.0f / __builtin_bit_cast(float, db);
                const int qrow = w * 32 + f * 16 + 4 * g + r;
                #pragma unroll
                for (int nf = 0; nf < 4; ++nf)
                    og[(size_t)qrow * DH + nf * 16 + c] = o[f][nf][r] * inv;
            }
        }
    } else {
        float* op = opart + ((size_t)(z * NH + h) * LSEQ + (size_t)qtile * QBLK) * DH;
        float* lprow = lpart + (size_t)(z * NH + h) * LSEQ + (size_t)qtile * QBLK;
        #pragma unroll
        for (int f = 0; f < 2; ++f) {
            #pragma unroll
            for (int r = 0; r < 4; ++r) {
                const int qrow = w * 32 + f * 16 + 4 * g + r;
                #pragma unroll
                for (int nf = 0; nf < 4; ++nf)
                    op[(size_t)qrow * DH + nf * 16 + c] = o[f][nf][r];
            }
            if (lane < 16)
                lprow[w * 32 + f * 16 + lane] = lp[f];
        }
    }
}

// merge 2 splits: out = (O0+O1) / (l0+l1)
__global__ __launch_bounds__(256)
void reduce_split(const float* __restrict__ opart, const float* __restrict__ lpart,
                  float* __restrict__ out) {
    const size_t OSZ  = (size_t)NH * LSEQ * DH;     // floats per split
    const size_t LSZ  = (size_t)NH * LSEQ;
    const size_t TOT4 = OSZ / 4;
    for (size_t i4 = (size_t)blockIdx.x * blockDim.x + threadIdx.x; i4 < TOT4;
         i4 += (size_t)gridDim.x * blockDim.x) {
        const size_t i   = i4 * 4;
        const size_t row = i >> 6;                  // / DH
        float4 a = *(const float4*)&opart[i];
        float4 b = *(const float4*)&opart[OSZ + i];
        float inv = 1.0f / (lpart[row] + lpart[LSZ + row]);
        float4 r;
        r.x = (a.x + b.x) * inv; r.y = (a.y + b.y) * inv;
        r.z = (a.z + b.z) * inv; r.w = (a.w + b.w) * inv;
        *(float4*)&out[i] = r;
    }
}

extern "C" void kernel_launch(void* const* d_in, const int* in_sizes, int n_in,
                              void* d_out, int out_size, void* d_ws, size_t ws_size,
                              hipStream_t stream) {
    const float* q = (const float*)d_in[0];
    const float* k = (const float*)d_in[1];
    const float* v = (const float*)d_in[2];
    float* out = (float*)d_out;

    const size_t OSZ = (size_t)NH * LSEQ * DH;      // floats per split
    const size_t LSZ = (size_t)NH * LSEQ;
    const size_t need = (2 * OSZ + 2 * LSZ) * sizeof(float);

    if (ws_size >= need) {
        float* opart = (float*)d_ws;
        float* lpart = opart + 2 * OSZ;
        attn_fwd<2><<<dim3(LSEQ / QBLK, NH, 2), dim3(512), 0, stream>>>(q, k, v, out, opart, lpart);
        reduce_split<<<dim3(2048), dim3(256), 0, stream>>>(opart, lpart, out);
    } else {
        attn_fwd<1><<<dim3(LSEQ / QBLK, NH, 1), dim3(512), 0, stream>>>(q, k, v, out, nullptr, nullptr);
    }
}